// Round 1
// baseline (963.827 us; speedup 1.0000x reference)
//
#include <hip/hip_runtime.h>
#include <stdint.h>

#define B_   16
#define L_   2048
#define D_   256
#define NROW (B_*L_)

typedef __attribute__((ext_vector_type(8))) short s8v;   // 8 x bf16 (as shorts)
typedef __attribute__((ext_vector_type(4))) float f4v;   // MFMA accumulator

__device__ __forceinline__ unsigned short f2b(float f) {
    unsigned u = __builtin_bit_cast(unsigned, f);
    return (unsigned short)((u + 0x7fffu + ((u >> 16) & 1u)) >> 16);
}

// ---------------- K1: fused QKV projection ----------------
// grid (512 row-blocks, 4 col-blocks, 3 types[Q,K,V]), block 256.
// Computes out = in @ W^T with bf16 MFMA; writes Q/K bf16 row-major + norms
// (atomicAdd into zeroed qn/kn); V is written TRANSPOSED: Vt[b][d][k].
__global__ __launch_bounds__(256) void qkv_kernel(
    const float* __restrict__ x, const float* __restrict__ y,
    const float* __restrict__ Wq, const float* __restrict__ Wk, const float* __restrict__ Wv,
    unsigned short* __restrict__ Qb, unsigned short* __restrict__ Kb,
    unsigned short* __restrict__ Vt,
    float* __restrict__ qn, float* __restrict__ kn)
{
    __shared__ unsigned short Xs[64*256];   // 32 KB input tile (bf16)
    __shared__ unsigned short Ws[64*256];   // 32 KB weight tile (bf16)
    __shared__ unsigned short Ts[64*68];    // V transpose buffer (+pad)

    const int t  = threadIdx.x;
    const int r0 = blockIdx.x * 64;   // global row (flat b*L + pos)
    const int e0 = blockIdx.y * 64;   // output col block
    const int type = blockIdx.z;      // 0=Q 1=K 2=V

    const float* X = (type == 0) ? x : y;
    const float* W = (type == 0) ? Wq : (type == 1) ? Wk : Wv;

    // Stage X tile [64][256] and W tile [64][256] fp32 -> bf16 LDS, coalesced float4.
    #pragma unroll
    for (int p = 0; p < 16; ++p) {
        int idx = p*256 + t;
        int row = idx >> 6;
        int c4  = (idx & 63) * 4;
        float4 vx = *(const float4*)(X + (size_t)(r0+row)*D_ + c4);
        uint2 px;
        px.x = (unsigned)f2b(vx.x) | ((unsigned)f2b(vx.y) << 16);
        px.y = (unsigned)f2b(vx.z) | ((unsigned)f2b(vx.w) << 16);
        *(uint2*)(Xs + row*256 + c4) = px;
        float4 vw = *(const float4*)(W + (size_t)(e0+row)*D_ + c4);
        uint2 pw;
        pw.x = (unsigned)f2b(vw.x) | ((unsigned)f2b(vw.y) << 16);
        pw.y = (unsigned)f2b(vw.z) | ((unsigned)f2b(vw.w) << 16);
        *(uint2*)(Ws + row*256 + c4) = pw;
    }
    __syncthreads();

    const int w = t >> 6, lane = t & 63, q16 = lane & 15, quad = lane >> 4;
    const int m0 = w * 16;   // wave's 16-row band

    f4v z4 = {0.f, 0.f, 0.f, 0.f};
    f4v acc[4];
    #pragma unroll
    for (int n = 0; n < 4; ++n) acc[n] = z4;

    // out[m][e] = sum_d X[m][d] * W[e][d]:  A = X (m x d), B[d][e] = W[e][d]
    #pragma unroll
    for (int c = 0; c < 8; ++c) {
        s8v a = *(const s8v*)(Xs + (m0 + q16)*256 + c*32 + quad*8);
        #pragma unroll
        for (int n = 0; n < 4; ++n) {
            s8v bb = *(const s8v*)(Ws + (n*16 + q16)*256 + c*32 + quad*8);
            acc[n] = __builtin_amdgcn_mfma_f32_16x16x32_bf16(a, bb, acc[n], 0, 0, 0);
        }
    }

    if (type < 2) {
        unsigned short* Out = (type == 0) ? Qb : Kb;
        float* norm = (type == 0) ? qn : kn;
        float p[4] = {0.f, 0.f, 0.f, 0.f};
        // C-layout: value (row = quad*4+r, col = n*16+q16)
        #pragma unroll
        for (int n = 0; n < 4; ++n)
            #pragma unroll
            for (int r = 0; r < 4; ++r) {
                float v = acc[n][r];
                p[r] += v * v;
                Out[(size_t)(r0 + m0 + quad*4 + r)*D_ + e0 + n*16 + q16] = f2b(v);
            }
        #pragma unroll
        for (int r = 0; r < 4; ++r) {
            float v = p[r];
            v += __shfl_xor(v, 1, 16);
            v += __shfl_xor(v, 2, 16);
            v += __shfl_xor(v, 4, 16);
            v += __shfl_xor(v, 8, 16);
            if (q16 == 0) atomicAdd(norm + r0 + m0 + quad*4 + r, v);
        }
    } else {
        // V: round-trip through LDS, write transposed Vt[b][d][k] coalesced.
        #pragma unroll
        for (int n = 0; n < 4; ++n)
            #pragma unroll
            for (int r = 0; r < 4; ++r)
                Ts[(m0 + quad*4 + r)*68 + n*16 + q16] = f2b(acc[n][r]);
        __syncthreads();
        int j = t >> 2;        // local d row 0..63
        int kseg = t & 3;      // 16 k's each
        unsigned pk[8];
        #pragma unroll
        for (int i = 0; i < 8; ++i) {
            unsigned lo = Ts[(kseg*16 + 2*i    )*68 + j];
            unsigned hi = Ts[(kseg*16 + 2*i + 1)*68 + j];
            pk[i] = lo | (hi << 16);
        }
        int bb_ = r0 >> 11;         // batch index
        int k0g = r0 & (L_ - 1);    // k offset within batch
        unsigned short* dst = Vt + (size_t)(bb_*D_ + e0 + j)*L_ + k0g + kseg*16;
        *(uint4*)dst       = make_uint4(pk[0], pk[1], pk[2], pk[3]);
        *((uint4*)dst + 1) = make_uint4(pk[4], pk[5], pk[6], pk[7]);
    }
}

// ---------------- K2: fused distance-attention ----------------
// grid (16 q-blocks, 16 batches), block 256 = 4 waves; wave owns 32 q rows
// (2 MFMA bands). Pass A: rowsums of E = exp(exp(-dist)). Pass B: recompute,
// write normalized attn, accumulate O = attn @ V via LDS-roundtripped E.
__global__ __launch_bounds__(256) void attn_kernel(
    const unsigned short* __restrict__ Qb, const unsigned short* __restrict__ Kb,
    const unsigned short* __restrict__ Vt,
    const float* __restrict__ qn, const float* __restrict__ kn,
    const unsigned char* __restrict__ mask,
    float* __restrict__ attn_out, float* __restrict__ att_out)
{
    __shared__ unsigned short Ks[32*256];   // 16 KB K tile (bf16)
    __shared__ unsigned short Vs[256*32];   // 16 KB Vt tile [d][k]
    __shared__ unsigned short Es[4][32*32]; // per-wave attn tile (A-layout src)
    __shared__ float kns[32];
    __shared__ unsigned char ms[2048];

    const int t = threadIdx.x;
    const int q0 = blockIdx.x * 128;
    const int b  = blockIdx.y;
    const int bk = b * L_;
    const int w = t >> 6, lane = t & 63, q16 = lane & 15, quad = lane >> 4;

    // stage mask row (2 KB) once
    *(unsigned long long*)(ms + t*8) = *(const unsigned long long*)(mask + bk + t*8);

    // Q fragments (A-layout, kept in registers) + q norms
    s8v qa[2][8];
    float qnr[2][4];
    #pragma unroll
    for (int e = 0; e < 2; ++e) {
        int row = bk + q0 + w*32 + e*16;
        #pragma unroll
        for (int c = 0; c < 8; ++c)
            qa[e][c] = *(const s8v*)(Qb + (size_t)(row + q16)*D_ + c*32 + quad*8);
        #pragma unroll
        for (int r = 0; r < 4; ++r)
            qnr[e][r] = qn[row + quad*4 + r];
    }

    float rs[2][4] = {};

    // ---------- pass A: row sums ----------
    for (int kt = 0; kt < 64; ++kt) {
        int k0 = kt * 32;
        #pragma unroll
        for (int p = 0; p < 4; ++p) {
            int idx = p*256 + t;
            int row = idx >> 5;
            int c8  = (idx & 31) * 8;
            *(uint4*)(Ks + row*256 + c8) =
                *(const uint4*)(Kb + (size_t)(bk + k0 + row)*D_ + c8);
        }
        if (t < 32) kns[t] = kn[bk + k0 + t];
        __syncthreads();
        #pragma unroll
        for (int e = 0; e < 2; ++e) {
            #pragma unroll
            for (int n = 0; n < 2; ++n) {
                f4v s = {0.f, 0.f, 0.f, 0.f};
                #pragma unroll
                for (int c = 0; c < 8; ++c) {
                    s8v bb = *(const s8v*)(Ks + (n*16 + q16)*256 + c*32 + quad*8);
                    s = __builtin_amdgcn_mfma_f32_16x16x32_bf16(qa[e][c], bb, s, 0, 0, 0);
                }
                float kc = kns[n*16 + q16];
                bool mk = ms[k0 + n*16 + q16] != 0;
                #pragma unroll
                for (int r = 0; r < 4; ++r) {
                    float d2 = qnr[e][r] + kc - 2.0f * s[r];
                    float dist = sqrtf(fmaxf(d2, 0.f));
                    float E = mk ? 0.f : __expf(__expf(-dist));
                    rs[e][r] += E;
                }
            }
        }
        __syncthreads();
    }

    // reduce row sums across the 16 lanes of each quad-group -> 1/rowsum
    float inv[2][4];
    #pragma unroll
    for (int e = 0; e < 2; ++e)
        #pragma unroll
        for (int r = 0; r < 4; ++r) {
            float v = rs[e][r];
            v += __shfl_xor(v, 1, 16);
            v += __shfl_xor(v, 2, 16);
            v += __shfl_xor(v, 4, 16);
            v += __shfl_xor(v, 8, 16);
            inv[e][r] = 1.0f / v;
        }

    f4v z4 = {0.f, 0.f, 0.f, 0.f};
    f4v O[2][16];
    #pragma unroll
    for (int e = 0; e < 2; ++e)
        #pragma unroll
        for (int n = 0; n < 16; ++n) O[e][n] = z4;

    // ---------- pass B: write normalized attn + accumulate O ----------
    for (int kt = 0; kt < 64; ++kt) {
        int k0 = kt * 32;
        #pragma unroll
        for (int p = 0; p < 4; ++p) {
            int idx = p*256 + t;
            int row = idx >> 5;
            int c8  = (idx & 31) * 8;
            *(uint4*)(Ks + row*256 + c8) =
                *(const uint4*)(Kb + (size_t)(bk + k0 + row)*D_ + c8);
        }
        #pragma unroll
        for (int p = 0; p < 4; ++p) {
            int idx = p*256 + t;
            int d   = idx >> 2;
            int seg = (idx & 3) * 8;
            *(uint4*)(Vs + d*32 + seg) =
                *(const uint4*)(Vt + (size_t)(b*D_ + d)*L_ + k0 + seg);
        }
        if (t < 32) kns[t] = kn[bk + k0 + t];
        __syncthreads();

        #pragma unroll
        for (int e = 0; e < 2; ++e) {
            #pragma unroll
            for (int n = 0; n < 2; ++n) {
                f4v s = {0.f, 0.f, 0.f, 0.f};
                #pragma unroll
                for (int c = 0; c < 8; ++c) {
                    s8v bb = *(const s8v*)(Ks + (n*16 + q16)*256 + c*32 + quad*8);
                    s = __builtin_amdgcn_mfma_f32_16x16x32_bf16(qa[e][c], bb, s, 0, 0, 0);
                }
                float kc = kns[n*16 + q16];
                bool mk = ms[k0 + n*16 + q16] != 0;
                #pragma unroll
                for (int r = 0; r < 4; ++r) {
                    float d2 = qnr[e][r] + kc - 2.0f * s[r];
                    float dist = sqrtf(fmaxf(d2, 0.f));
                    float E = mk ? 0.f : __expf(__expf(-dist));
                    float av = E * inv[e][r];
                    attn_out[(size_t)(bk + q0 + w*32 + e*16 + quad*4 + r)*L_
                             + k0 + n*16 + q16] = av;
                    Es[w][(e*16 + quad*4 + r)*32 + n*16 + q16] = f2b(av);
                }
            }
        }
        // PV: A = normalized attn tile (from own-wave LDS), B = Vs[d][k]
        s8v af0 = *(const s8v*)(&Es[w][(q16     )*32 + quad*8]);
        s8v af1 = *(const s8v*)(&Es[w][(16 + q16)*32 + quad*8]);
        #pragma unroll
        for (int n = 0; n < 16; ++n) {
            s8v vb = *(const s8v*)(Vs + (n*16 + q16)*32 + quad*8);
            O[0][n] = __builtin_amdgcn_mfma_f32_16x16x32_bf16(af0, vb, O[0][n], 0, 0, 0);
            O[1][n] = __builtin_amdgcn_mfma_f32_16x16x32_bf16(af1, vb, O[1][n], 0, 0, 0);
        }
        __syncthreads();
    }

    // write att_out (already normalized)
    #pragma unroll
    for (int e = 0; e < 2; ++e)
        #pragma unroll
        for (int n = 0; n < 16; ++n)
            #pragma unroll
            for (int r = 0; r < 4; ++r)
                att_out[(size_t)(bk + q0 + w*32 + e*16 + quad*4 + r)*D_
                        + n*16 + q16] = O[e][n][r];
}

extern "C" void kernel_launch(void* const* d_in, const int* in_sizes, int n_in,
                              void* d_out, int out_size, void* d_ws, size_t ws_size,
                              hipStream_t stream) {
    (void)in_sizes; (void)n_in; (void)out_size; (void)ws_size;
    const float* x  = (const float*)d_in[0];
    const float* y  = (const float*)d_in[1];
    const unsigned char* mask = (const unsigned char*)d_in[2];
    const float* Wq = (const float*)d_in[3];
    const float* Wk = (const float*)d_in[4];
    const float* Wv = (const float*)d_in[5];

    // workspace layout: Qb | Kb | Vt (bf16, 16.78 MB each) | qn | kn (fp32)
    char* ws = (char*)d_ws;
    unsigned short* Qb = (unsigned short*)ws;
    unsigned short* Kb = Qb + (size_t)NROW * D_;
    unsigned short* Vt = Kb + (size_t)NROW * D_;
    float* qn = (float*)(ws + 3 * (size_t)NROW * D_ * 2);
    float* kn = qn + NROW;

    float* att_out = (float*)d_out;                       // [B, LQ, D]
    float* attn    = att_out + (size_t)NROW * D_;         // [B, LQ, LK]

    hipMemsetAsync(qn, 0, 2 * (size_t)NROW * sizeof(float), stream);
    qkv_kernel<<<dim3(512, 4, 3), 256, 0, stream>>>(x, y, Wq, Wk, Wv,
                                                    Qb, Kb, Vt, qn, kn);
    attn_kernel<<<dim3(16, 16), 256, 0, stream>>>(Qb, Kb, Vt, qn, kn, mask,
                                                  attn, att_out);
}

// Round 2
// 635.572 us; speedup vs baseline: 1.5165x; 1.5165x over previous
//
#include <hip/hip_runtime.h>
#include <stdint.h>

#define B_   16
#define L_   2048
#define D_   256
#define NROW (B_*L_)

#define KPAD 264   // Ks row stride (shorts): 528 B = 132 dw ≡ 4 mod 32 banks, 16B-aligned
#define VPAD 40    // Vs row stride: 80 B = 20 dw ≡ 20 mod 32, 16B-aligned
#define EPAD 40    // Es row stride
#define TPAD 66    // qkv transpose buffer row stride

typedef __attribute__((ext_vector_type(8))) short s8v;   // 8 x bf16 (as shorts)
typedef __attribute__((ext_vector_type(4))) float f4v;   // MFMA accumulator

__device__ __forceinline__ unsigned short f2b(float f) {
    unsigned u = __builtin_bit_cast(unsigned, f);
    return (unsigned short)((u + 0x7fffu + ((u >> 16) & 1u)) >> 16);
}

// ---------------- K1: QKV projection ----------------
// grid (512 row-blocks, 3 types[Q,K,V]), block 256 (4 waves).
// Block computes 64 rows x ALL 256 cols: X tile staged once, W col-tiles
// looped (W stays L2-hot). Q/K written bf16 row-major + full row norms
// (plain stores, no atomics). V written transposed: Vt[b][d][k].
__global__ __launch_bounds__(256) void qkv_kernel(
    const float* __restrict__ x, const float* __restrict__ y,
    const float* __restrict__ Wq, const float* __restrict__ Wk, const float* __restrict__ Wv,
    unsigned short* __restrict__ Qb, unsigned short* __restrict__ Kb,
    unsigned short* __restrict__ Vt,
    float* __restrict__ qn, float* __restrict__ kn)
{
    __shared__ unsigned short Xs[64*256];    // 32 KB input tile (bf16)
    __shared__ unsigned short Ws[64*256];    // 32 KB weight tile (bf16)
    __shared__ unsigned short Ts[64*TPAD];   // V transpose buffer

    const int t    = threadIdx.x;
    const int r0   = blockIdx.x * 64;   // global row (flat b*L + pos)
    const int type = blockIdx.y;        // 0=Q 1=K 2=V

    const float* X = (type == 0) ? x : y;
    const float* W = (type == 0) ? Wq : (type == 1) ? Wk : Wv;

    // Stage X tile [64][256] fp32 -> bf16 LDS, coalesced float4.
    #pragma unroll
    for (int p = 0; p < 16; ++p) {
        int idx = p*256 + t;
        int row = idx >> 6;
        int c4  = (idx & 63) * 4;
        float4 vx = *(const float4*)(X + (size_t)(r0+row)*D_ + c4);
        uint2 px;
        px.x = (unsigned)f2b(vx.x) | ((unsigned)f2b(vx.y) << 16);
        px.y = (unsigned)f2b(vx.z) | ((unsigned)f2b(vx.w) << 16);
        *(uint2*)(Xs + row*256 + c4) = px;
    }

    const int w = t >> 6, lane = t & 63, q16 = lane & 15, quad = lane >> 4;
    const int m0 = w * 16;   // wave's 16-row band

    float p4[4] = {0.f, 0.f, 0.f, 0.f};   // row-norm partials (Q/K)
    const f4v z4 = {0.f, 0.f, 0.f, 0.f};

    for (int ct = 0; ct < 4; ++ct) {
        const int e0 = ct * 64;
        __syncthreads();   // previous tile's readers done (also covers Xs stage on ct=0)
        #pragma unroll
        for (int p = 0; p < 16; ++p) {
            int idx = p*256 + t;
            int row = idx >> 6;
            int c4  = (idx & 63) * 4;
            float4 vw = *(const float4*)(W + (size_t)(e0+row)*D_ + c4);
            uint2 pw;
            pw.x = (unsigned)f2b(vw.x) | ((unsigned)f2b(vw.y) << 16);
            pw.y = (unsigned)f2b(vw.z) | ((unsigned)f2b(vw.w) << 16);
            *(uint2*)(Ws + row*256 + c4) = pw;
        }
        __syncthreads();

        f4v acc[4];
        #pragma unroll
        for (int n = 0; n < 4; ++n) acc[n] = z4;

        // out[m][e] = sum_d X[m][d]*W[e][d]
        #pragma unroll
        for (int c = 0; c < 8; ++c) {
            s8v a = *(const s8v*)(Xs + (m0 + q16)*256 + c*32 + quad*8);
            #pragma unroll
            for (int n = 0; n < 4; ++n) {
                s8v bb = *(const s8v*)(Ws + (n*16 + q16)*256 + c*32 + quad*8);
                acc[n] = __builtin_amdgcn_mfma_f32_16x16x32_bf16(a, bb, acc[n], 0, 0, 0);
            }
        }

        if (type < 2) {
            unsigned short* Out = (type == 0) ? Qb : Kb;
            // C-layout: value at (row = quad*4+r, col = n*16+q16)
            #pragma unroll
            for (int n = 0; n < 4; ++n)
                #pragma unroll
                for (int r = 0; r < 4; ++r) {
                    float v = acc[n][r];
                    p4[r] += v * v;
                    Out[(size_t)(r0 + m0 + quad*4 + r)*D_ + e0 + n*16 + q16] = f2b(v);
                }
        } else {
            // V: transpose via LDS, write Vt[b][d][k] coalesced.
            #pragma unroll
            for (int n = 0; n < 4; ++n)
                #pragma unroll
                for (int r = 0; r < 4; ++r)
                    Ts[(m0 + quad*4 + r)*TPAD + n*16 + q16] = f2b(acc[n][r]);
            __syncthreads();
            int j    = t >> 2;   // local d col 0..63
            int kseg = t & 3;    // 16 k's each
            unsigned pk[8];
            #pragma unroll
            for (int i = 0; i < 8; ++i) {
                unsigned lo = Ts[(kseg*16 + 2*i    )*TPAD + j];
                unsigned hi = Ts[(kseg*16 + 2*i + 1)*TPAD + j];
                pk[i] = lo | (hi << 16);
            }
            int bb_ = r0 >> 11;         // batch index
            int k0g = r0 & (L_ - 1);    // k offset within batch
            unsigned short* dst = Vt + (size_t)(bb_*D_ + e0 + j)*L_ + k0g + kseg*16;
            *(uint4*)dst       = make_uint4(pk[0], pk[1], pk[2], pk[3]);
            *((uint4*)dst + 1) = make_uint4(pk[4], pk[5], pk[6], pk[7]);
        }
    }

    if (type < 2) {
        float* norm = (type == 0) ? qn : kn;
        #pragma unroll
        for (int r = 0; r < 4; ++r) {
            float v = p4[r];
            v += __shfl_xor(v, 1, 16);
            v += __shfl_xor(v, 2, 16);
            v += __shfl_xor(v, 4, 16);
            v += __shfl_xor(v, 8, 16);
            if (q16 == 0) norm[r0 + m0 + quad*4 + r] = v;
        }
    }
}

// ---------------- K2: fused distance-attention ----------------
// grid (32 q-blocks, 16 batches) = 512 blocks = 2 blocks/CU (8 waves/CU).
// Block = 4 waves, wave owns 16 q rows. Pass A: rowsums of
// E = exp(exp(-dist)). Pass B: recompute, write normalized attn,
// accumulate O = attn @ V (A-frag via per-wave LDS roundtrip).
__global__ __launch_bounds__(256) void attn_kernel(
    const unsigned short* __restrict__ Qb, const unsigned short* __restrict__ Kb,
    const unsigned short* __restrict__ Vt,
    const float* __restrict__ qn, const float* __restrict__ kn,
    const unsigned char* __restrict__ mask,
    float* __restrict__ attn_out, float* __restrict__ att_out)
{
    __shared__ unsigned short Ks[32*KPAD];    // K tile (bf16), padded
    __shared__ unsigned short Vs[256*VPAD];   // Vt tile [d][k], padded
    __shared__ unsigned short Es[4][16*EPAD]; // per-wave attn tile
    __shared__ float kns[32];
    __shared__ unsigned char ms[2048];

    const int t  = threadIdx.x;
    const int q0 = blockIdx.x * 64;
    const int b  = blockIdx.y;
    const int bk = b * L_;
    const int w = t >> 6, lane = t & 63, q16 = lane & 15, quad = lane >> 4;

    // stage mask row (2 KB) once
    *(unsigned long long*)(ms + t*8) = *(const unsigned long long*)(mask + bk + t*8);

    // Q fragments (A-layout, registers) + q norms; wave's rows = q0 + w*16
    const int qrow = bk + q0 + w*16;
    s8v qa[8];
    float qnr[4];
    #pragma unroll
    for (int c = 0; c < 8; ++c)
        qa[c] = *(const s8v*)(Qb + (size_t)(qrow + q16)*D_ + c*32 + quad*8);
    #pragma unroll
    for (int r = 0; r < 4; ++r)
        qnr[r] = qn[qrow + quad*4 + r];

    float rs[4] = {};

    // ---------- pass A: row sums ----------
    for (int kt = 0; kt < 64; ++kt) {
        int k0 = kt * 32;
        #pragma unroll
        for (int p = 0; p < 4; ++p) {
            int idx = p*256 + t;
            int row = idx >> 5;
            int c8  = (idx & 31) * 8;
            *(uint4*)(Ks + row*KPAD + c8) =
                *(const uint4*)(Kb + (size_t)(bk + k0 + row)*D_ + c8);
        }
        if (t < 32) kns[t] = kn[bk + k0 + t];
        __syncthreads();
        #pragma unroll
        for (int n = 0; n < 2; ++n) {
            f4v s = {0.f, 0.f, 0.f, 0.f};
            #pragma unroll
            for (int c = 0; c < 8; ++c) {
                s8v bb = *(const s8v*)(Ks + (n*16 + q16)*KPAD + c*32 + quad*8);
                s = __builtin_amdgcn_mfma_f32_16x16x32_bf16(qa[c], bb, s, 0, 0, 0);
            }
            float kc = kns[n*16 + q16];
            bool mk = ms[k0 + n*16 + q16] != 0;
            #pragma unroll
            for (int r = 0; r < 4; ++r) {
                float d2 = qnr[r] + kc - 2.0f * s[r];
                float dist = sqrtf(fmaxf(d2, 0.f));
                rs[r] += mk ? 0.f : __expf(__expf(-dist));
            }
        }
        __syncthreads();
    }

    float inv[4];
    #pragma unroll
    for (int r = 0; r < 4; ++r) {
        float v = rs[r];
        v += __shfl_xor(v, 1, 16);
        v += __shfl_xor(v, 2, 16);
        v += __shfl_xor(v, 4, 16);
        v += __shfl_xor(v, 8, 16);
        inv[r] = 1.0f / v;
    }

    const f4v z4 = {0.f, 0.f, 0.f, 0.f};
    f4v O[16];
    #pragma unroll
    for (int n = 0; n < 16; ++n) O[n] = z4;

    // ---------- pass B: write normalized attn + accumulate O ----------
    for (int kt = 0; kt < 64; ++kt) {
        int k0 = kt * 32;
        #pragma unroll
        for (int p = 0; p < 4; ++p) {
            int idx = p*256 + t;
            int row = idx >> 5;
            int c8  = (idx & 31) * 8;
            *(uint4*)(Ks + row*KPAD + c8) =
                *(const uint4*)(Kb + (size_t)(bk + k0 + row)*D_ + c8);
        }
        #pragma unroll
        for (int p = 0; p < 4; ++p) {
            int idx = p*256 + t;
            int d   = idx >> 2;
            int seg = (idx & 3) * 8;
            *(uint4*)(Vs + d*VPAD + seg) =
                *(const uint4*)(Vt + (size_t)(b*D_ + d)*L_ + k0 + seg);
        }
        if (t < 32) kns[t] = kn[bk + k0 + t];
        __syncthreads();

        #pragma unroll
        for (int n = 0; n < 2; ++n) {
            f4v s = {0.f, 0.f, 0.f, 0.f};
            #pragma unroll
            for (int c = 0; c < 8; ++c) {
                s8v bb = *(const s8v*)(Ks + (n*16 + q16)*KPAD + c*32 + quad*8);
                s = __builtin_amdgcn_mfma_f32_16x16x32_bf16(qa[c], bb, s, 0, 0, 0);
            }
            float kc = kns[n*16 + q16];
            bool mk = ms[k0 + n*16 + q16] != 0;
            #pragma unroll
            for (int r = 0; r < 4; ++r) {
                float d2 = qnr[r] + kc - 2.0f * s[r];
                float dist = sqrtf(fmaxf(d2, 0.f));
                float E = mk ? 0.f : __expf(__expf(-dist));
                float av = E * inv[r];
                attn_out[(size_t)(qrow + quad*4 + r)*L_ + k0 + n*16 + q16] = av;
                Es[w][(quad*4 + r)*EPAD + n*16 + q16] = f2b(av);
            }
        }
        // PV: A = normalized attn tile (own-wave LDS), B = Vs[d][k]
        s8v af = *(const s8v*)(&Es[w][q16*EPAD + quad*8]);
        #pragma unroll
        for (int n = 0; n < 16; ++n) {
            s8v vb = *(const s8v*)(Vs + (n*16 + q16)*VPAD + quad*8);
            O[n] = __builtin_amdgcn_mfma_f32_16x16x32_bf16(af, vb, O[n], 0, 0, 0);
        }
        __syncthreads();
    }

    // write att_out (already normalized)
    #pragma unroll
    for (int n = 0; n < 16; ++n)
        #pragma unroll
        for (int r = 0; r < 4; ++r)
            att_out[(size_t)(qrow + quad*4 + r)*D_ + n*16 + q16] = O[n][r];
}

extern "C" void kernel_launch(void* const* d_in, const int* in_sizes, int n_in,
                              void* d_out, int out_size, void* d_ws, size_t ws_size,
                              hipStream_t stream) {
    (void)in_sizes; (void)n_in; (void)out_size; (void)ws_size;
    const float* x  = (const float*)d_in[0];
    const float* y  = (const float*)d_in[1];
    const unsigned char* mask = (const unsigned char*)d_in[2];
    const float* Wq = (const float*)d_in[3];
    const float* Wk = (const float*)d_in[4];
    const float* Wv = (const float*)d_in[5];

    // workspace layout: Qb | Kb | Vt (bf16, 16.78 MB each) | qn | kn (fp32)
    char* ws = (char*)d_ws;
    unsigned short* Qb = (unsigned short*)ws;
    unsigned short* Kb = Qb + (size_t)NROW * D_;
    unsigned short* Vt = Kb + (size_t)NROW * D_;
    float* qn = (float*)(ws + 3 * (size_t)NROW * D_ * 2);
    float* kn = qn + NROW;

    float* att_out = (float*)d_out;                       // [B, LQ, D]
    float* attn    = att_out + (size_t)NROW * D_;         // [B, LQ, LK]

    qkv_kernel<<<dim3(512, 3), 256, 0, stream>>>(x, y, Wq, Wk, Wv,
                                                 Qb, Kb, Vt, qn, kn);
    attn_kernel<<<dim3(32, 16), 256, 0, stream>>>(Qb, Kb, Vt, qn, kn, mask,
                                                  attn, att_out);
}

// Round 3
// 612.829 us; speedup vs baseline: 1.5727x; 1.0371x over previous
//
#include <hip/hip_runtime.h>
#include <stdint.h>

#define B_   16
#define L_   2048
#define D_   256
#define NROW (B_*L_)

#define EPAD 40    // Es row stride (shorts)
#define TPAD 66    // qkv transpose buffer row stride

typedef __attribute__((ext_vector_type(8))) short s8v;   // 8 x bf16 (as shorts)
typedef __attribute__((ext_vector_type(4))) float f4v;   // MFMA accumulator

__device__ __forceinline__ unsigned short f2b(float f) {   // RNE f32->bf16
    unsigned u = __builtin_bit_cast(unsigned, f);
    return (unsigned short)((u + 0x7fffu + ((u >> 16) & 1u)) >> 16);
}

// async global->LDS, 16B per lane; LDS dest = wave-uniform base + lane*16
__device__ __forceinline__ void gl16(const void* g, void* l) {
    __builtin_amdgcn_global_load_lds(
        (const __attribute__((address_space(1))) unsigned int*)g,
        (__attribute__((address_space(3))) unsigned int*)l, 16, 0, 0);
}

// ---------------- K1: QKV projection ----------------
// grid (512 row-blocks, 2 types), block 256 (4 waves).
// type0: Q from x.  type1: K and V from y (y staged once).
// Xs/Ws reads XOR-swizzled in 16B chunks to kill pow2-stride bank conflicts.
__global__ __launch_bounds__(256) void qkv_kernel(
    const float* __restrict__ x, const float* __restrict__ y,
    const float* __restrict__ Wq, const float* __restrict__ Wk, const float* __restrict__ Wv,
    unsigned short* __restrict__ Qb, unsigned short* __restrict__ Kb,
    unsigned short* __restrict__ Vt,
    float* __restrict__ qn, float* __restrict__ kn)
{
    __shared__ unsigned short Xs[64*256];    // 32 KB input tile (bf16)
    __shared__ unsigned short Ws[64*256];    // 32 KB weight tile (bf16)
    __shared__ unsigned short Ts[64*TPAD];   // V transpose buffer

    const int t    = threadIdx.x;
    const int r0   = blockIdx.x * 64;   // global row (flat b*L + pos)
    const int type = blockIdx.y;        // 0=Q  1=K+V

    const float* X = type ? y : x;

    // Stage X tile [64][256] fp32 -> bf16 LDS, 16B-chunk swizzled by row&15.
    #pragma unroll
    for (int p = 0; p < 16; ++p) {
        int idx  = p*256 + t;
        int row  = idx >> 6;
        int half = idx & 1;              // which 8B half of the 16B chunk
        int blk  = (idx & 63) >> 1;      // 16B chunk index 0..31
        int c4   = blk*8 + half*4;       // source column (shorts/floats)
        float4 vx = *(const float4*)(X + (size_t)(r0+row)*D_ + c4);
        uint2 px;
        px.x = (unsigned)f2b(vx.x) | ((unsigned)f2b(vx.y) << 16);
        px.y = (unsigned)f2b(vx.z) | ((unsigned)f2b(vx.w) << 16);
        *(uint2*)(Xs + row*256 + (blk ^ (row & 15))*8 + half*4) = px;
    }

    const int w = t >> 6, lane = t & 63, q16 = lane & 15, quad = lane >> 4;
    const int m0 = w * 16;   // wave's 16-row band

    float p4[4] = {0.f, 0.f, 0.f, 0.f};   // row-norm partials (Q/K)
    const f4v z4 = {0.f, 0.f, 0.f, 0.f};

    for (int ct = 0; ct < 4; ++ct) {
        const int e0 = ct * 64;

        // ---- Q (type0) or K (type1) weight tile ----
        __syncthreads();   // previous tile's readers done (covers Xs stage on ct=0)
        {
            const float* W = type ? Wk : Wq;
            #pragma unroll
            for (int p = 0; p < 16; ++p) {
                int idx  = p*256 + t;
                int row  = idx >> 6;
                int half = idx & 1;
                int blk  = (idx & 63) >> 1;
                int c4   = blk*8 + half*4;
                float4 vw = *(const float4*)(W + (size_t)(e0+row)*D_ + c4);
                uint2 pw;
                pw.x = (unsigned)f2b(vw.x) | ((unsigned)f2b(vw.y) << 16);
                pw.y = (unsigned)f2b(vw.z) | ((unsigned)f2b(vw.w) << 16);
                *(uint2*)(Ws + row*256 + (blk ^ (row & 15))*8 + half*4) = pw;
            }
        }
        __syncthreads();

        f4v acc[4];
        #pragma unroll
        for (int n = 0; n < 4; ++n) acc[n] = z4;
        #pragma unroll
        for (int c = 0; c < 8; ++c) {
            s8v a = *(const s8v*)(Xs + (m0 + q16)*256 + (((c*4+quad) ^ q16)*8));
            #pragma unroll
            for (int n = 0; n < 4; ++n) {
                s8v bb = *(const s8v*)(Ws + (n*16 + q16)*256 + (((c*4+quad) ^ q16)*8));
                acc[n] = __builtin_amdgcn_mfma_f32_16x16x32_bf16(a, bb, acc[n], 0, 0, 0);
            }
        }
        {
            unsigned short* Out = type ? Kb : Qb;
            // C-layout: value at (row = quad*4+r, col = n*16+q16)
            #pragma unroll
            for (int n = 0; n < 4; ++n)
                #pragma unroll
                for (int r = 0; r < 4; ++r) {
                    float v = acc[n][r];
                    p4[r] += v * v;
                    Out[(size_t)(r0 + m0 + quad*4 + r)*D_ + e0 + n*16 + q16] = f2b(v);
                }
        }

        if (type) {
            // ---- V weight tile ----
            __syncthreads();   // K-mfma readers of Ws done
            #pragma unroll
            for (int p = 0; p < 16; ++p) {
                int idx  = p*256 + t;
                int row  = idx >> 6;
                int half = idx & 1;
                int blk  = (idx & 63) >> 1;
                int c4   = blk*8 + half*4;
                float4 vw = *(const float4*)(Wv + (size_t)(e0+row)*D_ + c4);
                uint2 pw;
                pw.x = (unsigned)f2b(vw.x) | ((unsigned)f2b(vw.y) << 16);
                pw.y = (unsigned)f2b(vw.z) | ((unsigned)f2b(vw.w) << 16);
                *(uint2*)(Ws + row*256 + (blk ^ (row & 15))*8 + half*4) = pw;
            }
            __syncthreads();

            f4v vacc[4];
            #pragma unroll
            for (int n = 0; n < 4; ++n) vacc[n] = z4;
            #pragma unroll
            for (int c = 0; c < 8; ++c) {
                s8v a = *(const s8v*)(Xs + (m0 + q16)*256 + (((c*4+quad) ^ q16)*8));
                #pragma unroll
                for (int n = 0; n < 4; ++n) {
                    s8v bb = *(const s8v*)(Ws + (n*16 + q16)*256 + (((c*4+quad) ^ q16)*8));
                    vacc[n] = __builtin_amdgcn_mfma_f32_16x16x32_bf16(a, bb, vacc[n], 0, 0, 0);
                }
            }
            // transpose via LDS, write Vt[b][d][k] coalesced
            #pragma unroll
            for (int n = 0; n < 4; ++n)
                #pragma unroll
                for (int r = 0; r < 4; ++r)
                    Ts[(m0 + quad*4 + r)*TPAD + n*16 + q16] = f2b(vacc[n][r]);
            __syncthreads();
            int j    = t >> 2;   // local d col 0..63
            int kseg = t & 3;    // 16 k's each
            unsigned pk[8];
            #pragma unroll
            for (int i = 0; i < 8; ++i) {
                unsigned lo = Ts[(kseg*16 + 2*i    )*TPAD + j];
                unsigned hi = Ts[(kseg*16 + 2*i + 1)*TPAD + j];
                pk[i] = lo | (hi << 16);
            }
            int bb_ = r0 >> 11;         // batch index
            int k0g = r0 & (L_ - 1);    // k offset within batch
            unsigned short* dst = Vt + (size_t)(bb_*D_ + e0 + j)*L_ + k0g + kseg*16;
            *(uint4*)dst       = make_uint4(pk[0], pk[1], pk[2], pk[3]);
            *((uint4*)dst + 1) = make_uint4(pk[4], pk[5], pk[6], pk[7]);
        }
    }

    {
        float* norm = type ? kn : qn;
        #pragma unroll
        for (int r = 0; r < 4; ++r) {
            float v = p4[r];
            v += __shfl_xor(v, 1, 16);
            v += __shfl_xor(v, 2, 16);
            v += __shfl_xor(v, 4, 16);
            v += __shfl_xor(v, 8, 16);
            if (q16 == 0) norm[r0 + m0 + quad*4 + r] = v;
        }
    }
}

// ---- shared staging helpers (DMA direct to LDS, XOR-swizzled global src) ----
// Ks: 32 rows x 256 cols bf16; 16B chunk blk stored at global blk^(row&15)
__device__ __forceinline__ void stage_K(const unsigned short* Kb, unsigned short* ks,
                                        int bk, int k0, int w, int lane) {
    #pragma unroll
    for (int p = 0; p < 4; ++p) {
        int slot = p*256 + w*64 + lane;
        int row  = slot >> 5;
        int blk  = slot & 31;
        gl16(Kb + (size_t)(bk + k0 + row)*D_ + ((blk ^ (row & 15))*8),
             ks + (size_t)(p*256 + w*64)*8);
    }
}
// Vs: 256 rows(d) x 32 cols(k) bf16; chunk blk (0..3) swizzled by (d>>1)&3
__device__ __forceinline__ void stage_V(const unsigned short* Vt, unsigned short* vs,
                                        int bD, int k0, int w, int lane) {
    #pragma unroll
    for (int p = 0; p < 4; ++p) {
        int slot = p*256 + w*64 + lane;
        int d    = slot >> 2;
        int blk  = slot & 3;
        gl16(Vt + (size_t)(bD + d)*L_ + k0 + ((blk ^ ((d >> 1) & 3))*8),
             vs + (size_t)(p*256 + w*64)*8);
    }
}

// ---------------- K2a: rowsum of E = exp(exp(-dist)) ----------------
// grid (32 qb, 16 b, 2 kslice) = 1024 blocks (4/CU, 16 waves/CU).
// Single-barrier double-buffered DMA K-loop; atomicAdd partial rowsums.
__global__ __launch_bounds__(256) void rowsum_kernel(
    const unsigned short* __restrict__ Qb, const unsigned short* __restrict__ Kb,
    const float* __restrict__ qn, const float* __restrict__ kn,
    const unsigned char* __restrict__ mask,
    float* __restrict__ rowsum)
{
    __shared__ unsigned short Ks[2][32*256];   // 16 KB each

    const int t  = threadIdx.x;
    const int q0 = blockIdx.x * 64;
    const int b  = blockIdx.y;
    const int bk = b * L_;
    const int kbase = blockIdx.z * 1024;
    const int w = t >> 6, lane = t & 63, q16 = lane & 15, quad = lane >> 4;

    const int qrow = bk + q0 + w*16;
    s8v qa[8];
    float qnr[4];
    #pragma unroll
    for (int c = 0; c < 8; ++c)
        qa[c] = *(const s8v*)(Qb + (size_t)(qrow + q16)*D_ + c*32 + quad*8);
    #pragma unroll
    for (int r = 0; r < 4; ++r)
        qnr[r] = qn[qrow + quad*4 + r];

    float rs[4] = {0.f, 0.f, 0.f, 0.f};

    stage_K(Kb, Ks[0], bk, kbase, w, lane);
    for (int kt = 0; kt < 32; ++kt) {
        const int k0 = kbase + kt*32;
        const int cur = kt & 1;
        __syncthreads();                       // drains own DMAs -> Ks[cur] ready
        if (kt < 31) stage_K(Kb, Ks[cur ^ 1], bk, k0 + 32, w, lane);

        float kcv[2]; int mkv[2];
        #pragma unroll
        for (int n = 0; n < 2; ++n) {
            kcv[n] = kn[bk + k0 + n*16 + q16];
            mkv[n] = mask[bk + k0 + n*16 + q16];
        }
        #pragma unroll
        for (int n = 0; n < 2; ++n) {
            f4v s = {0.f, 0.f, 0.f, 0.f};
            #pragma unroll
            for (int c = 0; c < 8; ++c) {
                s8v bb = *(const s8v*)(Ks[cur] + (n*16 + q16)*256 + (((c*4+quad) ^ q16)*8));
                s = __builtin_amdgcn_mfma_f32_16x16x32_bf16(qa[c], bb, s, 0, 0, 0);
            }
            #pragma unroll
            for (int r = 0; r < 4; ++r) {
                float d2 = qnr[r] + kcv[n] - 2.0f * s[r];
                float dist = sqrtf(fmaxf(d2, 0.f));
                rs[r] += mkv[n] ? 0.f : __expf(__expf(-dist));
            }
        }
    }

    #pragma unroll
    for (int r = 0; r < 4; ++r) {
        float v = rs[r];
        v += __shfl_xor(v, 1, 16);
        v += __shfl_xor(v, 2, 16);
        v += __shfl_xor(v, 4, 16);
        v += __shfl_xor(v, 8, 16);
        if (q16 == 0) atomicAdd(rowsum + qrow + quad*4 + r, v);
    }
}

// ---------------- K2b: normalized attn + O = attn @ V ----------------
// grid (32 qb, 16 b), block 256 (4 waves x 16 q-rows). Single-barrier
// double-buffered DMA loop: QK -> scores -> write attn -> per-wave Es
// roundtrip -> PV accumulate.
__global__ __launch_bounds__(256) void attnout_kernel(
    const unsigned short* __restrict__ Qb, const unsigned short* __restrict__ Kb,
    const unsigned short* __restrict__ Vt,
    const float* __restrict__ qn, const float* __restrict__ kn,
    const float* __restrict__ rowsum,
    const unsigned char* __restrict__ mask,
    float* __restrict__ attn_out, float* __restrict__ att_out)
{
    __shared__ unsigned short Ks[2][32*256];    // 16 KB each
    __shared__ unsigned short Vs[2][256*32];    // 16 KB each
    __shared__ unsigned short Es[4][16*EPAD];   // per-wave attn tile (5 KB)

    const int t  = threadIdx.x;
    const int q0 = blockIdx.x * 64;
    const int b  = blockIdx.y;
    const int bk = b * L_;
    const int bD = b * D_;
    const int w = t >> 6, lane = t & 63, q16 = lane & 15, quad = lane >> 4;

    const int qrow = bk + q0 + w*16;
    s8v qa[8];
    float qnr[4], inv[4];
    #pragma unroll
    for (int c = 0; c < 8; ++c)
        qa[c] = *(const s8v*)(Qb + (size_t)(qrow + q16)*D_ + c*32 + quad*8);
    #pragma unroll
    for (int r = 0; r < 4; ++r) {
        qnr[r] = qn[qrow + quad*4 + r];
        inv[r] = 1.0f / rowsum[qrow + quad*4 + r];
    }

    const f4v z4 = {0.f, 0.f, 0.f, 0.f};
    f4v O[16];
    #pragma unroll
    for (int n = 0; n < 16; ++n) O[n] = z4;

    stage_K(Kb, Ks[0], bk, 0, w, lane);
    stage_V(Vt, Vs[0], bD, 0, w, lane);
    for (int kt = 0; kt < 64; ++kt) {
        const int k0 = kt * 32;
        const int cur = kt & 1;
        __syncthreads();                       // Ks/Vs[cur] ready; prev bufs free
        if (kt < 63) {
            stage_K(Kb, Ks[cur ^ 1], bk, k0 + 32, w, lane);
            stage_V(Vt, Vs[cur ^ 1], bD, k0 + 32, w, lane);
        }

        float kcv[2]; int mkv[2];
        #pragma unroll
        for (int n = 0; n < 2; ++n) {
            kcv[n] = kn[bk + k0 + n*16 + q16];
            mkv[n] = mask[bk + k0 + n*16 + q16];
        }

        #pragma unroll
        for (int n = 0; n < 2; ++n) {
            f4v s = {0.f, 0.f, 0.f, 0.f};
            #pragma unroll
            for (int c = 0; c < 8; ++c) {
                s8v bb = *(const s8v*)(Ks[cur] + (n*16 + q16)*256 + (((c*4+quad) ^ q16)*8));
                s = __builtin_amdgcn_mfma_f32_16x16x32_bf16(qa[c], bb, s, 0, 0, 0);
            }
            #pragma unroll
            for (int r = 0; r < 4; ++r) {
                float d2 = qnr[r] + kcv[n] - 2.0f * s[r];
                float dist = sqrtf(fmaxf(d2, 0.f));
                float E = mkv[n] ? 0.f : __expf(__expf(-dist));
                float av = E * inv[r];
                attn_out[(size_t)(qrow + quad*4 + r)*L_ + k0 + n*16 + q16] = av;
                // truncation-rounded bf16 (error budget is huge here)
                Es[w][(quad*4 + r)*EPAD + n*16 + q16] =
                    (unsigned short)(__builtin_bit_cast(unsigned, av) >> 16);
            }
        }
        // PV: A = own-wave Es (same-wave write->read, lgkmcnt ordered)
        s8v af = *(const s8v*)(&Es[w][q16*EPAD + quad*8]);
        #pragma unroll
        for (int n = 0; n < 16; ++n) {
            s8v vb = *(const s8v*)(Vs[cur] + (n*16 + q16)*32 +
                                   ((quad ^ ((q16 >> 1) & 3))*8));
            O[n] = __builtin_amdgcn_mfma_f32_16x16x32_bf16(af, vb, O[n], 0, 0, 0);
        }
    }

    #pragma unroll
    for (int n = 0; n < 16; ++n)
        #pragma unroll
        for (int r = 0; r < 4; ++r)
            att_out[(size_t)(qrow + quad*4 + r)*D_ + n*16 + q16] = O[n][r];
}

extern "C" void kernel_launch(void* const* d_in, const int* in_sizes, int n_in,
                              void* d_out, int out_size, void* d_ws, size_t ws_size,
                              hipStream_t stream) {
    (void)in_sizes; (void)n_in; (void)out_size; (void)ws_size;
    const float* x  = (const float*)d_in[0];
    const float* y  = (const float*)d_in[1];
    const unsigned char* mask = (const unsigned char*)d_in[2];
    const float* Wq = (const float*)d_in[3];
    const float* Wk = (const float*)d_in[4];
    const float* Wv = (const float*)d_in[5];

    // ws: Qb | Kb | Vt (bf16, 16.78 MB each) | qn | kn | rowsum (fp32)
    char* ws = (char*)d_ws;
    unsigned short* Qb = (unsigned short*)ws;
    unsigned short* Kb = Qb + (size_t)NROW * D_;
    unsigned short* Vt = Kb + (size_t)NROW * D_;
    float* qn     = (float*)(ws + 3 * (size_t)NROW * D_ * 2);
    float* kn     = qn + NROW;
    float* rowsum = kn + NROW;

    float* att_out = (float*)d_out;                       // [B, LQ, D]
    float* attn    = att_out + (size_t)NROW * D_;         // [B, LQ, LK]

    hipMemsetAsync(rowsum, 0, (size_t)NROW * sizeof(float), stream);
    qkv_kernel<<<dim3(512, 2), 256, 0, stream>>>(x, y, Wq, Wk, Wv,
                                                 Qb, Kb, Vt, qn, kn);
    rowsum_kernel<<<dim3(32, 16, 2), 256, 0, stream>>>(Qb, Kb, qn, kn, mask, rowsum);
    attnout_kernel<<<dim3(32, 16), 256, 0, stream>>>(Qb, Kb, Vt, qn, kn, rowsum,
                                                     mask, attn, att_out);
}